// Round 16
// baseline (108.340 us; speedup 1.0000x reference)
//
#include <hip/hip_runtime.h>
#include <hip/hip_bf16.h>
#include <stdint.h>

#define Bb 8
#define Ss 2048
#define Dd 4096
#define Ee 64
#define CAP 40
#define M_TOK (Bb*Ss)                    // 16384 tokens
#define TOP1_OFF  (M_TOK*Ee)             // 1048576
#define PROBS_OFF (TOP1_OFF + M_TOK)     // 1064960
#define AUX_OFF   (PROBS_OFF + M_TOK*Ee) // 2113536
#define ND_OFF    (AUX_OFF + 1)

// ws byte offsets
#define W2_OFF   0u                      // 1 MB chunk-major W hi/lo
#define PART_OFF (1u<<20)                // 16 MB fp32 partials [tg][ks4][64][64]
#define CNTT_OFF (17u<<20)               // 64 KB int   cntT[b][e][32]
#define PIT_OFF  ((17u<<20) + (64u<<10)) // 64 KB float piT [b][e][32]
#define EID_OFF  ((17u<<20) + (128u<<10))// 64 KB int   eid[tok]

typedef __attribute__((ext_vector_type(8))) short short8;
typedef __attribute__((ext_vector_type(4))) float f32x4;

// pin vmem issue order across this point (IR + MIR schedulers)
#define FENCE() do {                                                          \
    asm volatile("" ::: "memory");                                            \
    __builtin_amdgcn_sched_barrier(0);                                        \
  } while (0)

__device__ __forceinline__ void cvt8hl(const float4 a, const float4 b,
                                       short8& hi, short8& lo) {
  __hip_bfloat162 h0 = __float22bfloat162_rn(make_float2(a.x, a.y));
  __hip_bfloat162 h1 = __float22bfloat162_rn(make_float2(a.z, a.w));
  __hip_bfloat162 h2 = __float22bfloat162_rn(make_float2(b.x, b.y));
  __hip_bfloat162 h3 = __float22bfloat162_rn(make_float2(b.z, b.w));
  float2 f0 = __bfloat1622float2(h0), f1 = __bfloat1622float2(h1);
  float2 f2 = __bfloat1622float2(h2), f3 = __bfloat1622float2(h3);
  __hip_bfloat162 l0 = __float22bfloat162_rn(make_float2(a.x - f0.x, a.y - f0.y));
  __hip_bfloat162 l1 = __float22bfloat162_rn(make_float2(a.z - f1.x, a.w - f1.y));
  __hip_bfloat162 l2 = __float22bfloat162_rn(make_float2(b.x - f2.x, b.y - f2.y));
  __hip_bfloat162 l3 = __float22bfloat162_rn(make_float2(b.z - f3.x, b.w - f3.y));
  union U { __hip_bfloat162 h[4]; short8 s; };
  U uh; uh.h[0] = h0; uh.h[1] = h1; uh.h[2] = h2; uh.h[3] = h3; hi = uh.s;
  U ul; ul.h[0] = l0; ul.h[1] = l1; ul.h[2] = l2; ul.h[3] = l3; lo = ul.s;
}

// ---- k0: W [k][e] fp32 -> chunk-major hi/lo bf16 fragments -----------------
// k32-chunk C at byte C*8192: [g(4)][hl(2)][lane(64)x16B]
__global__ __launch_bounds__(256) void k0_wsplit(const float* __restrict__ W,
                                                 char* __restrict__ w2) {
  const int id  = blockIdx.x * 256 + threadIdx.x;   // 32768 items
  const int l   = id & 63;
  const int g   = (id >> 6) & 3;
  const int sub = (id >> 8) & 1;
  const int c   = id >> 9;
  const int e   = g * 16 + (l & 15);
  const int kb  = c * 64 + sub * 32 + (l >> 4) * 8;
  float xs[8];
#pragma unroll
  for (int j = 0; j < 8; ++j) xs[j] = W[(size_t)(kb + j) * Ee + e];
  short8 hi, lo;
  cvt8hl(make_float4(xs[0], xs[1], xs[2], xs[3]),
         make_float4(xs[4], xs[5], xs[6], xs[7]), hi, lo);
  char* base = w2 + (size_t)c * 16384 + sub * 8192 + g * 2048 + l * 16;
  *(short8*)base = hi;
  *(short8*)(base + 1024) = lo;
}

// ---- k1: ALL loads via global_load_lds; quad-buffer, 3-deep, one wait ------
// grid 1024: tg = bid>>2, ks = bid&3. Per chunk (BK=32) stage W 8KB + A 8KB
// into wb[4][16KB]. A stored [row64][slot8 x 16B] with slot^=(row&7) XOR
// (swizzle applied on the gll SOURCE address; LDS linear -- m173 pattern).
// The wave's ONLY vmem = gll -> single vmcnt(12)/iter retires stage S(t)
// issued 3 iters (~700-1000 cyc) earlier: HBM latency covered per-wave.
// Ledger: prologue S(0..3); iter t: vmcnt(12) -> barrier -> S(t+4)(t<=27)
// -> COMP(t). Tails t=29/30/31 -> vmcnt(8/4/0). WAR: S(t+4) writes
// buf[(t+4)&3]=buf[t&3]... wait: 4 buffers, S(t+4) -> buf[t&3] is the buf
// being READ in iter t -- NO: (t+4)&3 == t&3! Therefore stage depth 3 needs
// buf count 4 with S(t+3) (not t+4): prologue S(0..2), issue S(t+3) t<=28,
// queue top of t = S(t..t+2)=12 -> vmcnt(8). Tails t=30->4, t=31->0.
// WAR: S(t+3)->buf[(t-1)&3], read iter t-1, separated by barrier(t). SAFE.
__global__ __launch_bounds__(256, 2) void k1_gemm(
    const float* __restrict__ H, const char* __restrict__ w2,
    float* __restrict__ part) {
  __shared__ char wb[4][16384];                    // [W 8KB | A 8KB] x 4
  const int tid = threadIdx.x;
  const int wv = tid >> 6, l = tid & 63;
  const int tg = blockIdx.x >> 2, ks = blockIdx.x & 3;
  const int tb = tg * 64;
  // W gll source (r13 layout): per-thread quarter of the 8KB chunk
  const char* wsrc = w2 + (size_t)ks * 262144 + wv * 2048 + l * 16;
  // A gll sources: pass p stages rows p*32 + wv*8 + (l>>3), slot u=l&7,
  // content slot v = u ^ (row&7); row&7 == l>>3 (wv*8, 32 are mult of 8)
  const int swz = ((l & 7) ^ (l >> 3)) * 4;        // floats
  const float* asrc0 = H + (size_t)(tb + wv * 8 + (l >> 3)) * Dd
                         + ks * 1024 + swz;
  const float* asrc1 = asrc0 + (size_t)32 * Dd;

  f32x4 acc[4];
#pragma unroll
  for (int g = 0; g < 4; ++g) acc[g] = (f32x4){0.f, 0.f, 0.f, 0.f};
  short8 ah0, al0;

#define GLL16(gs, ls)                                                         \
  __builtin_amdgcn_global_load_lds(                                           \
      (const __attribute__((address_space(1))) unsigned int*)(gs),            \
      (__attribute__((address_space(3))) unsigned int*)(ls), 16, 0, 0)

  // 4 gll per thread per stage: 2 W + 2 A
#define STAGE(t, bi) {                                                        \
    const char* sw_ = wsrc + (size_t)(t) * 8192;                              \
    char* dw_ = &wb[bi][wv * 2048];                                           \
    GLL16(sw_, dw_); GLL16(sw_ + 1024, dw_ + 1024);                           \
    const float* sa0_ = asrc0 + (t) * 32;                                     \
    const float* sa1_ = asrc1 + (t) * 32;                                     \
    char* da0_ = &wb[bi][8192 + wv * 1024];                                   \
    char* da1_ = &wb[bi][8192 + 4096 + wv * 1024];                            \
    GLL16(sa0_, da0_); GLL16(sa1_, da1_); }

#define MFMA4(ac, ah, al, wh, wl) {                                           \
    ac = __builtin_amdgcn_mfma_f32_16x16x32_bf16(ah, wh, ac, 0, 0, 0);        \
    ac = __builtin_amdgcn_mfma_f32_16x16x32_bf16(ah, wl, ac, 0, 0, 0);        \
    ac = __builtin_amdgcn_mfma_f32_16x16x32_bf16(al, wh, ac, 0, 0, 0);        \
    ac = __builtin_amdgcn_mfma_f32_16x16x32_bf16(al, wl, ac, 0, 0, 0); }

  const int arow = wv * 16 + (l & 15);             // this lane's A row
  const int aslot0 = ((2 * (l >> 4))     ^ (arow & 7)) * 16;
  const int aslot1 = ((2 * (l >> 4) + 1) ^ (arow & 7)) * 16;

#define COMPM(bi) {                                                           \
    const char* ab_ = &wb[bi][8192] + arow * 128;                             \
    const float4 fa_ = *(const float4*)(ab_ + aslot0);                        \
    const float4 fb_ = *(const float4*)(ab_ + aslot1);                        \
    cvt8hl(fa_, fb_, ah0, al0);                                               \
    const char* wp_ = &wb[bi][0] + l * 16;                                    \
    _Pragma("unroll")                                                         \
    for (int g = 0; g < 4; ++g) {                                             \
      const short8 wh = *(const short8*)(wp_ + g * 2048);                     \
      const short8 wl = *(const short8*)(wp_ + g * 2048 + 1024);              \
      MFMA4(acc[g], ah0, al0, wh, wl);                                        \
    } }

  // prologue: S(0), S(1), S(2) (oldest first)
  STAGE(0, 0);
  FENCE();
  STAGE(1, 1);
  FENCE();
  STAGE(2, 2);
  FENCE();

#pragma unroll
  for (int t = 0; t < 32; ++t) {
    // single wait: retire S(t) (12 ops = S(t+1),S(t+2) remain outstanding)
    if (t <= 29)      { asm volatile("s_waitcnt vmcnt(8)" ::: "memory"); }
    else if (t == 30) { asm volatile("s_waitcnt vmcnt(4)" ::: "memory"); }
    else              { asm volatile("s_waitcnt vmcnt(0)" ::: "memory"); }
    FENCE();
    __builtin_amdgcn_s_barrier();                  // publish S(t) to block
    if (t <= 28) STAGE(t + 3, (t + 3) & 3);        // fire-and-forget
    FENCE();
    COMPM(t & 3);
  }

  // partial logits -> ws (fp32), [tg][ks][tok64][e]
  float* pp = part + (size_t)(tg * 4 + ks) * 4096;
#pragma unroll
  for (int g = 0; g < 4; ++g)
#pragma unroll
    for (int r = 0; r < 4; ++r)
      pp[(wv * 16 + (l >> 4) * 4 + r) * 64 + g * 16 + (l & 15)] = acc[g][r];
}

// ---- k1b: sum 4 k-partials + bias, softmax, argmax, chunk stats ------------
__global__ __launch_bounds__(512) void k1b_softmax(
    const float* __restrict__ part, const float* __restrict__ bias,
    float* __restrict__ out, int* __restrict__ cntT, float* __restrict__ piT,
    int* __restrict__ eid_ws) {
  __shared__ int   csh[512];
  __shared__ float psh[512];
  const int tid = threadIdx.x, wv = tid >> 6, l = tid & 63;
  const int tg = blockIdx.x;
  const float* p0 = part + (size_t)tg * 16384;

  int cnt = 0; float pis = 0.f;
  const float bl_ = bias[l];
#pragma unroll
  for (int i = 0; i < 8; ++i) {                 // wave owns 8 tokens
    const int t = wv * 8 + i, tok = tg * 64 + t;
    const float v = p0[t * 64 + l] + p0[4096 + t * 64 + l] +
                    p0[8192 + t * 64 + l] + p0[12288 + t * 64 + l] + bl_;
    float m = v; int mi = l;
#pragma unroll
    for (int off = 32; off >= 1; off >>= 1) {   // max + first-index argmax
      const float ov = __shfl_xor(m, off);
      const int   oi = __shfl_xor(mi, off);
      if (ov > m || (ov == m && oi < mi)) { m = ov; mi = oi; }
    }
    const float ex = __expf(v - m);
    float ssum = ex;
#pragma unroll
    for (int off = 32; off >= 1; off >>= 1) ssum += __shfl_xor(ssum, off);
    const float inv = 1.0f / ssum;
    const float p = ex * inv;
    out[(size_t)PROBS_OFF + (size_t)tok * Ee + l] = p;
    if (l == 0) {
      out[TOP1_OFF + tok] = inv;                // max prob = 1/sum
      eid_ws[tok] = mi;
    }
    cnt += (mi == l) ? 1 : 0;
    pis += p;
  }
  csh[wv * 64 + l] = cnt;
  psh[wv * 64 + l] = pis;
  __syncthreads();
  if (tid < 64) {
    int ct = 0; float pp = 0.f;
#pragma unroll
    for (int w = 0; w < 8; ++w) { ct += csh[w * 64 + tid]; pp += psh[w * 64 + tid]; }
    cntT[((size_t)(tg >> 5) * 64 + tid) * 32 + (tg & 31)] = ct;
    piT [((size_t)(tg >> 5) * 64 + tid) * 32 + (tg & 31)] = pp;
  }
}

// ---- k3: capacity mask (inline prefix) + one-hot write + aux/dropped -------
__global__ __launch_bounds__(64) void k3_indices(
    const int* __restrict__ cntT, const float* __restrict__ piT,
    const int* __restrict__ eid_ws, float* __restrict__ out) {
  __shared__ float tile[64][64];
  const int g = blockIdx.x, lane = threadIdx.x; // 64-token chunk
  const int b = g >> 5, cc = g & 31;
  const int tok = g * 64 + lane;
  const int e = eid_ws[tok];

  unsigned long long mymask = 0ull;             // same-expert mask in chunk
  for (int j = 0; j < 64; ++j) {
    const int ej = __shfl(e, j);
    const unsigned long long bal = __ballot(ej == e);
    if (j == lane) mymask = bal;
  }
  const int lrank = __popcll(mymask & ((1ull << lane) - 1ull));

  // prefix over earlier chunks: lane reads its expert's 32 counts (contig)
  const int4* cp = (const int4*)(cntT + ((size_t)b * 64 + e) * 32);
  int prefix = 0;
#pragma unroll
  for (int j = 0; j < 8; ++j) {
    const int4 v = cp[j];
    const int base = 4 * j;
    prefix += ((base + 0 < cc) ? v.x : 0) + ((base + 1 < cc) ? v.y : 0)
            + ((base + 2 < cc) ? v.z : 0) + ((base + 3 < cc) ? v.w : 0);
  }
  const float keep = (prefix + lrank < CAP) ? 1.0f : 0.0f;

#pragma unroll
  for (int j = 0; j < 64; ++j) tile[j][lane] = 0.f;
  __syncthreads();
  tile[lane][e] = keep;
  __syncthreads();

  float4*       og = (float4*)(out + (size_t)g * 64 * 64);
  const float4* ts = (const float4*)&tile[0][0];
#pragma unroll
  for (int i = 0; i < 16; ++i) og[i * 64 + lane] = ts[i * 64 + lane];

  if (g == 0) {                                 // aux loss + num_dropped
    float auxsum = 0.f; int dropped = 0;
    for (int bb = 0; bb < 8; ++bb) {
      const int4*   cq = (const int4*)  (cntT + ((size_t)bb * 64 + lane) * 32);
      const float4* pq = (const float4*)(piT  + ((size_t)bb * 64 + lane) * 32);
      int tot = 0; float ps = 0.f;
#pragma unroll
      for (int j = 0; j < 8; ++j) {
        const int4 v = cq[j];   tot += v.x + v.y + v.z + v.w;
        const float4 w = pq[j]; ps  += w.x + w.y + w.z + w.w;
      }
      dropped += (tot > CAP) ? (tot - CAP) : 0;
      const float fi = (float)((tot < CAP) ? tot : CAP) * (1.0f / (float)Ss);
      const float pi = ps * (1.0f / (float)Ss);
      float fp = fi * pi;
#pragma unroll
      for (int off = 32; off >= 1; off >>= 1) fp += __shfl_xor(fp, off);
      auxsum += fp;                             // all lanes hold batch sum
    }
#pragma unroll
    for (int off = 32; off >= 1; off >>= 1) dropped += __shfl_xor(dropped, off);
    if (lane == 0) {
      out[AUX_OFF] = (float)Ee * auxsum / (float)Bb;
      out[ND_OFF]  = (float)dropped;
    }
  }
}

extern "C" void kernel_launch(void* const* d_in, const int* in_sizes, int n_in,
                              void* d_out, int out_size, void* d_ws, size_t ws_size,
                              hipStream_t stream) {
  const float* H    = (const float*)d_in[0];
  const float* Wm   = (const float*)d_in[1];
  const float* bias = (const float*)d_in[2];
  float* out = (float*)d_out;
  char*  w2   = (char*) d_ws + W2_OFF;
  float* part = (float*)((char*)d_ws + PART_OFF);
  int*   cntT = (int*)  ((char*)d_ws + CNTT_OFF);
  float* piT  = (float*)((char*)d_ws + PIT_OFF);
  int*   eid  = (int*)  ((char*)d_ws + EID_OFF);

  hipLaunchKernelGGL(k0_wsplit,   dim3(128),  dim3(256), 0, stream, Wm, w2);
  hipLaunchKernelGGL(k1_gemm,     dim3(1024), dim3(256), 0, stream, H, w2, part);
  hipLaunchKernelGGL(k1b_softmax, dim3(256),  dim3(512), 0, stream,
                     part, bias, out, cntT, piT, eid);
  hipLaunchKernelGGL(k3_indices,  dim3(256),  dim3(64),  0, stream,
                     cntT, piT, eid, out);
}